// Round 1
// baseline (2125.657 us; speedup 1.0000x reference)
//
#include <hip/hip_runtime.h>
#include <math.h>

#define EPSF 1e-8f

constexpr int Bn = 16, Cc = 256, HW = 1024, Ee = 512, Vv = 8192;
constexpr int Mm = Bn * HW; // 16384 pixels

// d_out float offsets: z | z_q | decoder_input | tokens(float)
constexpr long O_Z   = 0;
constexpr long O_ZQ  = 8388608;
constexpr long O_DEC = 16777216;
constexpr long O_TOK = 25165824;

// ---------------- small prep kernels ----------------

__global__ void k_wT(const float* __restrict__ w, float* __restrict__ wT) {
    int gid = blockIdx.x * 256 + threadIdx.x;      // 0..131071
    int c = gid >> 9, e = gid & 511;
    wT[gid] = w[e * Cc + c];                        // wT[c][e]
}

__global__ void k_en(const float* __restrict__ emb, float* __restrict__ en_inv,
                     float* __restrict__ en_norm) {
    int v = blockIdx.x * 4 + (threadIdx.x >> 6);    // one wave per row
    int lane = threadIdx.x & 63;
    const float* row = emb + (long)v * Ee;
    float s = 0.f;
#pragma unroll
    for (int j = 0; j < 8; ++j) { float xv = row[lane + 64 * j]; s += xv * xv; }
#pragma unroll
    for (int off = 32; off; off >>= 1) s += __shfl_xor(s, off);
    if (lane == 0) {
        float n = sqrtf(s);
        en_norm[v] = EPSF + n;
        en_inv[v]  = 1.0f / (EPSF + n);
    }
}

// embT[k][v] = emb[v][k] * en_inv[v]   (normalized transpose)
__global__ void k_embT(const float* __restrict__ emb, const float* __restrict__ en_inv,
                       float* __restrict__ embT) {
    __shared__ float tile[64][65];
    int v0 = (blockIdx.x >> 3) * 64;   // 128 v-tiles
    int k0 = (blockIdx.x & 7) * 64;    // 8 k-tiles
    int t = threadIdx.x;
#pragma unroll
    for (int q = 0; q < 4; ++q) {
        int f = t + 256 * q;
        int i = f >> 4, j4 = (f & 15) * 4;
        float4 d = *(const float4*)(emb + (long)(v0 + i) * Ee + k0 + j4);
        float inv = en_inv[v0 + i];
        tile[j4 + 0][i] = d.x * inv;
        tile[j4 + 1][i] = d.y * inv;
        tile[j4 + 2][i] = d.z * inv;
        tile[j4 + 3][i] = d.w * inv;
    }
    __syncthreads();
#pragma unroll
    for (int q = 0; q < 4; ++q) {
        int f = t + 256 * q;
        int j = f >> 4, i4 = (f & 15) * 4;
        float4 o;
        o.x = tile[j][i4]; o.y = tile[j][i4 + 1]; o.z = tile[j][i4 + 2]; o.w = tile[j][i4 + 3];
        *(float4*)(embT + (long)(k0 + j) * Vv + v0 + i4) = o;
    }
}

// ---------------- GEMM1: z[b][e][hw] = sum_c x[b][c][hw]*w[e][c] + b[e] ----------------

__global__ __launch_bounds__(256) void k_gemm1(const float* __restrict__ x,
                                               const float* __restrict__ wT,
                                               const float* __restrict__ bias,
                                               float* __restrict__ z) {
    __shared__ float As[32][64];
    __shared__ float Bs[32][64];
    int m0 = blockIdx.x * 64;                 // pixel tile
    int b = m0 >> 10, hw0 = m0 & 1023;
    int e0 = blockIdx.y * 64;
    int t = threadIdx.x;
    int mi = t >> 4, ni = t & 15;
    float acc[4][4] = {};
    for (int c0 = 0; c0 < Cc; c0 += 32) {
#pragma unroll
        for (int q = 0; q < 2; ++q) {
            int f = t + 256 * q;
            int kk = f >> 4, m4 = (f & 15) * 4;
            *(float4*)&As[kk][m4] = *(const float4*)(x + ((long)(b * Cc + c0 + kk)) * HW + hw0 + m4);
            *(float4*)&Bs[kk][m4] = *(const float4*)(wT + (long)(c0 + kk) * Ee + e0 + m4);
        }
        __syncthreads();
#pragma unroll
        for (int kk = 0; kk < 32; ++kk) {
            float4 a = *(float4*)&As[kk][mi * 4];
            float4 bv = *(float4*)&Bs[kk][ni * 4];
            float av[4] = {a.x, a.y, a.z, a.w};
            float bb[4] = {bv.x, bv.y, bv.z, bv.w};
#pragma unroll
            for (int r = 0; r < 4; ++r)
#pragma unroll
                for (int c = 0; c < 4; ++c) acc[r][c] = fmaf(av[r], bb[c], acc[r][c]);
        }
        __syncthreads();
    }
#pragma unroll
    for (int c = 0; c < 4; ++c) {
        int e = e0 + ni * 4 + c;
        float be = bias[e];
        float4 o = make_float4(acc[0][c] + be, acc[1][c] + be, acc[2][c] + be, acc[3][c] + be);
        *(float4*)(z + ((long)(b * Ee + e)) * HW + hw0 + mi * 4) = o;
    }
}

// per-pixel 1/(EPS+||z||) over E
__global__ void k_znorm(const float* __restrict__ z, float* __restrict__ inv_zn) {
    int p = blockIdx.x * 256 + threadIdx.x;
    int b = p >> 10, hw = p & 1023;
    const float* base = z + (long)b * Ee * HW + hw;
    float s = 0.f;
    for (int e = 0; e < Ee; ++e) { float xv = base[(long)e * HW]; s += xv * xv; }
    inv_zn[p] = 1.0f / (EPSF + sqrtf(s));
}

// ---------------- GEMM2 + argmax: the 137 GF kernel ----------------
// 256 blocks (1/CU), 256 threads. zn tile [K=512][M=64] resident in LDS.
// embT streamed in [8][256] double-buffered chunks, float4-slot XOR swizzle.

__device__ __forceinline__ int swz(int f4) { return f4 ^ ((f4 >> 3) & 7); }

__global__ __launch_bounds__(256, 1) void k_argmax(const float* __restrict__ z,
                                                   const float* __restrict__ inv_zn,
                                                   const float* __restrict__ embT,
                                                   int* __restrict__ tok_i,
                                                   float* __restrict__ tok_f) {
    __shared__ float zn_s[512][64];       // 128 KB
    __shared__ float emb_s[2][8][256];    // 16 KB
    int t = threadIdx.x;
    int p0 = blockIdx.x * 64;
    int b = p0 >> 10, hw0 = p0 & 1023;

    { // stage zn (scaled) once
        int m4 = (t & 15) * 4;
        float4 inv = *(const float4*)(inv_zn + p0 + m4);
#pragma unroll 4
        for (int q = 0; q < 32; ++q) {
            int e = (t >> 4) + 16 * q;
            float4 d = *(const float4*)(z + ((long)(b * Ee + e)) * HW + hw0 + m4);
            d.x *= inv.x; d.y *= inv.y; d.z *= inv.z; d.w *= inv.w;
            *(float4*)&zn_s[e][m4] = d;
        }
    }
    int mi = t >> 5;   // 0..7  -> rows 8*mi..+7
    int ni = t & 31;   // 0..31 -> cols 8*ni..+7 within V-tile
    float best[8]; int bidx[8];
#pragma unroll
    for (int r = 0; r < 8; ++r) { best[r] = -1e30f; bidx[r] = 0; }
    __syncthreads();

    const int f0 = t, f1 = t + 256;
    const int kk0 = f0 >> 6, s0 = swz(f0 & 63);
    const int kk1 = f1 >> 6, s1 = swz(f1 & 63);
    const int sa = swz(2 * ni), sb = swz(2 * ni + 1);

    for (int vt = 0; vt < Vv / 256; ++vt) {
        int v0 = vt * 256;
        float acc[8][8] = {};
        { // chunk 0
            float4 r0 = *(const float4*)(embT + (long)kk0 * Vv + v0 + 4 * (f0 & 63));
            float4 r1 = *(const float4*)(embT + (long)kk1 * Vv + v0 + 4 * (f1 & 63));
            *(float4*)&emb_s[0][kk0][4 * s0] = r0;
            *(float4*)&emb_s[0][kk1][4 * s1] = r1;
        }
        __syncthreads();
        for (int kc = 0; kc < 64; ++kc) {
            int cur = kc & 1;
            float4 n0, n1;
            if (kc < 63) {
                int k0 = (kc + 1) * 8;
                n0 = *(const float4*)(embT + (long)(k0 + kk0) * Vv + v0 + 4 * (f0 & 63));
                n1 = *(const float4*)(embT + (long)(k0 + kk1) * Vv + v0 + 4 * (f1 & 63));
            }
#pragma unroll
            for (int kk = 0; kk < 8; ++kk) {
                int k = kc * 8 + kk;
                float4 a0 = *(float4*)&zn_s[k][8 * mi];
                float4 a1 = *(float4*)&zn_s[k][8 * mi + 4];
                float4 b0 = *(float4*)&emb_s[cur][kk][4 * sa];
                float4 b1 = *(float4*)&emb_s[cur][kk][4 * sb];
                float av[8] = {a0.x, a0.y, a0.z, a0.w, a1.x, a1.y, a1.z, a1.w};
                float bv[8] = {b0.x, b0.y, b0.z, b0.w, b1.x, b1.y, b1.z, b1.w};
#pragma unroll
                for (int r = 0; r < 8; ++r)
#pragma unroll
                    for (int c = 0; c < 8; ++c) acc[r][c] = fmaf(av[r], bv[c], acc[r][c]);
            }
            if (kc < 63) {
                int nxt = cur ^ 1;
                *(float4*)&emb_s[nxt][kk0][4 * s0] = n0;
                *(float4*)&emb_s[nxt][kk1][4 * s1] = n1;
            }
            __syncthreads();
        }
        // fold tile into running argmax (ascending v + strict > == first-max)
#pragma unroll
        for (int r = 0; r < 8; ++r)
#pragma unroll
            for (int c = 0; c < 8; ++c) {
                float val = acc[r][c];
                if (val > best[r]) { best[r] = val; bidx[r] = v0 + 8 * ni + c; }
            }
    }
    // reduce across the 32 ni-lanes sharing each mi (tie -> smaller index)
#pragma unroll
    for (int r = 0; r < 8; ++r) {
        float v = best[r]; int i = bidx[r];
#pragma unroll
        for (int off = 1; off < 32; off <<= 1) {
            float ov = __shfl_xor(v, off);
            int oi = __shfl_xor(i, off);
            if (ov > v || (ov == v && oi < i)) { v = ov; i = oi; }
        }
        if (ni == 0) {
            int p = p0 + 8 * mi + r;
            tok_i[p] = i;
            tok_f[p] = (float)i;
        }
    }
}

// ---------------- finalize: z_q gather + straight-through blend ----------------

__global__ void k_final(const float* __restrict__ z, const float* __restrict__ emb,
                        const int* __restrict__ tok, const float* __restrict__ inv_zn,
                        const float* __restrict__ en_inv, const float* __restrict__ en_norm,
                        float* __restrict__ zq, float* __restrict__ dec) {
    long gid = (long)blockIdx.x * 256 + threadIdx.x;   // 0..8388607
    int hw = (int)(gid & 1023);
    int b  = (int)(gid >> 19);
    int p  = (b << 10) | hw;
    int e  = (int)((gid >> 10) & 511);
    int tk = tok[p];
    float zqv = emb[(long)tk * Ee + e];
    float nq  = en_norm[tk];
    float nzq = zqv * en_inv[tk];
    float zv  = z[gid];
    float nz  = zv * inv_zn[p];
    zq[gid]  = zqv;
    dec[gid] = (nz + (nzq - nz)) * nq;
}

// ---------------- launch ----------------

extern "C" void kernel_launch(void* const* d_in, const int* in_sizes, int n_in,
                              void* d_out, int out_size, void* d_ws, size_t ws_size,
                              hipStream_t stream) {
    const float* x     = (const float*)d_in[0];
    const float* w_pre = (const float*)d_in[1];
    const float* b_pre = (const float*)d_in[2];
    const float* emb   = (const float*)d_in[3];

    float* out  = (float*)d_out;
    float* z    = out + O_Z;
    float* zq   = out + O_ZQ;
    float* dec  = out + O_DEC;
    float* tokf = out + O_TOK;
    float* embT = zq;            // z_q region reused as scratch until k_final

    float* ws      = (float*)d_ws;      // ~720 KB of d_ws used
    float* wT      = ws;                // 131072
    float* en_inv  = wT + 131072;       // 8192
    float* en_norm = en_inv + 8192;     // 8192
    float* inv_zn  = en_norm + 8192;    // 16384
    int*   tok_i   = (int*)(inv_zn + 16384); // 16384

    k_wT<<<512, 256, 0, stream>>>(w_pre, wT);
    k_en<<<2048, 256, 0, stream>>>(emb, en_inv, en_norm);
    k_embT<<<1024, 256, 0, stream>>>(emb, en_inv, embT);
    dim3 g1(Mm / 64, Ee / 64);
    k_gemm1<<<g1, 256, 0, stream>>>(x, wT, b_pre, z);
    k_znorm<<<Mm / 256, 256, 0, stream>>>(z, inv_zn);
    k_argmax<<<Mm / 64, 256, 0, stream>>>(z, inv_zn, embT, tok_i, tokf);
    k_final<<<(int)(8388608 / 256), 256, 0, stream>>>(z, emb, tok_i, inv_zn, en_inv, en_norm, zq, dec);
}

// Round 2
// 1772.569 us; speedup vs baseline: 1.1992x; 1.1992x over previous
//
#include <hip/hip_runtime.h>
#include <math.h>

#define EPSF 1e-8f

constexpr int Bn = 16, Cc = 256, HW = 1024, Ee = 512, Vv = 8192;
constexpr int Mm = Bn * HW; // 16384 pixels

// d_out float offsets: z | z_q | decoder_input | tokens(float)
constexpr long O_Z   = 0;
constexpr long O_ZQ  = 8388608;
constexpr long O_DEC = 16777216;
constexpr long O_TOK = 25165824;

// ---------------- small prep kernels ----------------

__global__ void k_wT(const float* __restrict__ w, float* __restrict__ wT) {
    int gid = blockIdx.x * 256 + threadIdx.x;      // 0..131071
    int c = gid >> 9, e = gid & 511;
    wT[gid] = w[e * Cc + c];                        // wT[c][e]
}

__global__ void k_en(const float* __restrict__ emb, float* __restrict__ en_inv,
                     float* __restrict__ en_norm) {
    int v = blockIdx.x * 4 + (threadIdx.x >> 6);    // one wave per row
    int lane = threadIdx.x & 63;
    const float* row = emb + (long)v * Ee;
    float s = 0.f;
#pragma unroll
    for (int j = 0; j < 8; ++j) { float xv = row[lane + 64 * j]; s += xv * xv; }
#pragma unroll
    for (int off = 32; off; off >>= 1) s += __shfl_xor(s, off);
    if (lane == 0) {
        float n = sqrtf(s);
        en_norm[v] = EPSF + n;
        en_inv[v]  = 1.0f / (EPSF + n);
    }
}

// embT[k][v] = emb[v][k] * en_inv[v]   (normalized transpose)
__global__ void k_embT(const float* __restrict__ emb, const float* __restrict__ en_inv,
                       float* __restrict__ embT) {
    __shared__ float tile[64][65];
    int v0 = (blockIdx.x >> 3) * 64;   // 128 v-tiles
    int k0 = (blockIdx.x & 7) * 64;    // 8 k-tiles
    int t = threadIdx.x;
#pragma unroll
    for (int q = 0; q < 4; ++q) {
        int f = t + 256 * q;
        int i = f >> 4, j4 = (f & 15) * 4;
        float4 d = *(const float4*)(emb + (long)(v0 + i) * Ee + k0 + j4);
        float inv = en_inv[v0 + i];
        tile[j4 + 0][i] = d.x * inv;
        tile[j4 + 1][i] = d.y * inv;
        tile[j4 + 2][i] = d.z * inv;
        tile[j4 + 3][i] = d.w * inv;
    }
    __syncthreads();
#pragma unroll
    for (int q = 0; q < 4; ++q) {
        int f = t + 256 * q;
        int j = f >> 4, i4 = (f & 15) * 4;
        float4 o;
        o.x = tile[j][i4]; o.y = tile[j][i4 + 1]; o.z = tile[j][i4 + 2]; o.w = tile[j][i4 + 3];
        *(float4*)(embT + (long)(k0 + j) * Vv + v0 + i4) = o;
    }
}

// ---------------- GEMM1: z[b][e][hw] = sum_c x[b][c][hw]*w[e][c] + b[e] ----------------

__global__ __launch_bounds__(256) void k_gemm1(const float* __restrict__ x,
                                               const float* __restrict__ wT,
                                               const float* __restrict__ bias,
                                               float* __restrict__ z) {
    __shared__ float As[32][64];
    __shared__ float Bs[32][64];
    int m0 = blockIdx.x * 64;                 // pixel tile
    int b = m0 >> 10, hw0 = m0 & 1023;
    int e0 = blockIdx.y * 64;
    int t = threadIdx.x;
    int mi = t >> 4, ni = t & 15;
    float acc[4][4] = {};
    for (int c0 = 0; c0 < Cc; c0 += 32) {
#pragma unroll
        for (int q = 0; q < 2; ++q) {
            int f = t + 256 * q;
            int kk = f >> 4, m4 = (f & 15) * 4;
            *(float4*)&As[kk][m4] = *(const float4*)(x + ((long)(b * Cc + c0 + kk)) * HW + hw0 + m4);
            *(float4*)&Bs[kk][m4] = *(const float4*)(wT + (long)(c0 + kk) * Ee + e0 + m4);
        }
        __syncthreads();
#pragma unroll
        for (int kk = 0; kk < 32; ++kk) {
            float4 a = *(float4*)&As[kk][mi * 4];
            float4 bv = *(float4*)&Bs[kk][ni * 4];
            float av[4] = {a.x, a.y, a.z, a.w};
            float bb[4] = {bv.x, bv.y, bv.z, bv.w};
#pragma unroll
            for (int r = 0; r < 4; ++r)
#pragma unroll
                for (int c = 0; c < 4; ++c) acc[r][c] = fmaf(av[r], bb[c], acc[r][c]);
        }
        __syncthreads();
    }
#pragma unroll
    for (int c = 0; c < 4; ++c) {
        int e = e0 + ni * 4 + c;
        float be = bias[e];
        float4 o = make_float4(acc[0][c] + be, acc[1][c] + be, acc[2][c] + be, acc[3][c] + be);
        *(float4*)(z + ((long)(b * Ee + e)) * HW + hw0 + mi * 4) = o;
    }
}

// per-pixel 1/(EPS+||z||) over E
__global__ void k_znorm(const float* __restrict__ z, float* __restrict__ inv_zn) {
    int p = blockIdx.x * 256 + threadIdx.x;
    int b = p >> 10, hw = p & 1023;
    const float* base = z + (long)b * Ee * HW + hw;
    float s = 0.f;
    for (int e = 0; e < Ee; ++e) { float xv = base[(long)e * HW]; s += xv * xv; }
    inv_zn[p] = 1.0f / (EPSF + sqrtf(s));
}

// ---------------- GEMM2 + argmax ----------------
// 256 blocks, 512 threads (8 waves -> 2/SIMD). zn tile [512][64] in LDS.
// embT streamed as [2 K-rows][1024 cols] double-buffered chunks.
// Per-thread micro-tile: 16 rows x 8 cols. a-reads are wave-broadcast.

__device__ __forceinline__ int swz(int s) { return s ^ ((s >> 3) & 7); }

__global__ __launch_bounds__(512, 2) void k_argmax(const float* __restrict__ z,
                                                   const float* __restrict__ inv_zn,
                                                   const float* __restrict__ embT,
                                                   int* __restrict__ tok_i,
                                                   float* __restrict__ tok_f) {
    __shared__ float zn_s[512][64];        // 128 KB
    __shared__ float emb_s[2][2][1024];    // 16 KB
    __shared__ float red_v[8][16];
    __shared__ int   red_i[8][16];
    int t = threadIdx.x;
    int p0 = blockIdx.x * 64;
    int b = p0 >> 10, hw0 = p0 & 1023;

    { // stage zn (scaled) once
        int m4 = (t & 15) * 4;
        float4 inv = *(const float4*)(inv_zn + p0 + m4);
#pragma unroll 4
        for (int q = 0; q < 16; ++q) {
            int e = (t >> 4) + 32 * q;
            float4 d = *(const float4*)(z + ((long)(b * Ee + e)) * HW + hw0 + m4);
            d.x *= inv.x; d.y *= inv.y; d.z *= inv.z; d.w *= inv.w;
            *(float4*)&zn_s[e][m4] = d;
        }
    }
    const int mi = t >> 7;          // 0..3  -> rows 16*mi..+15 (wave-uniform)
    const int ni = t & 127;         // 0..127 -> cols 8*ni..+7 within 1024-wide vtile
    const int kr = t >> 8;          // 0..1   staging K-row
    const int c4 = t & 255;         // staging float4 col
    const int sw = 4 * swz(c4);
    const int sa = 4 * swz(2 * ni), sb = 4 * swz(2 * ni + 1);

    float best[16]; int bidx[16];
#pragma unroll
    for (int r = 0; r < 16; ++r) { best[r] = -1e30f; bidx[r] = 0; }

    for (int vt = 0; vt < 8; ++vt) {
        int v0 = vt * 1024;
        { // prologue: chunk 0 -> buf 0
            float4 r0 = *(const float4*)(embT + (long)kr * Vv + v0 + 4 * c4);
            *(float4*)&emb_s[0][kr][sw] = r0;
        }
        __syncthreads();
        float acc[16][8] = {};
        for (int kc = 0; kc < 256; ++kc) {
            int cur = kc & 1;
            float4 nx;
            if (kc < 255)
                nx = *(const float4*)(embT + (long)(2 * (kc + 1) + kr) * Vv + v0 + 4 * c4);
#pragma unroll
            for (int kk = 0; kk < 2; ++kk) {
                int k = kc * 2 + kk;
                float4 a0 = *(float4*)&zn_s[k][16 * mi];
                float4 a1 = *(float4*)&zn_s[k][16 * mi + 4];
                float4 a2 = *(float4*)&zn_s[k][16 * mi + 8];
                float4 a3 = *(float4*)&zn_s[k][16 * mi + 12];
                float4 b0 = *(float4*)&emb_s[cur][kk][sa];
                float4 b1 = *(float4*)&emb_s[cur][kk][sb];
                float av[16] = {a0.x, a0.y, a0.z, a0.w, a1.x, a1.y, a1.z, a1.w,
                                a2.x, a2.y, a2.z, a2.w, a3.x, a3.y, a3.z, a3.w};
                float bv[8] = {b0.x, b0.y, b0.z, b0.w, b1.x, b1.y, b1.z, b1.w};
#pragma unroll
                for (int r = 0; r < 16; ++r)
#pragma unroll
                    for (int c = 0; c < 8; ++c) acc[r][c] = fmaf(av[r], bv[c], acc[r][c]);
            }
            if (kc < 255)
                *(float4*)&emb_s[cur ^ 1][kr][sw] = nx;
            __syncthreads();
        }
        // fold tile into running argmax (ascending v + strict > == first-max)
#pragma unroll
        for (int r = 0; r < 16; ++r)
#pragma unroll
            for (int c = 0; c < 8; ++c) {
                float val = acc[r][c];
                if (val > best[r]) { best[r] = val; bidx[r] = v0 + 8 * ni + c; }
            }
    }
    // reduce across the 64 lanes of each wave (tie -> smaller index)
    int w = t >> 6, lane = t & 63;
#pragma unroll
    for (int r = 0; r < 16; ++r) {
        float v = best[r]; int i = bidx[r];
#pragma unroll
        for (int off = 1; off < 64; off <<= 1) {
            float ov = __shfl_xor(v, off);
            int oi = __shfl_xor(i, off);
            if (ov > v || (ov == v && oi < i)) { v = ov; i = oi; }
        }
        if (lane == 0) { red_v[w][r] = v; red_i[w][r] = i; }
    }
    __syncthreads();
    // waves 2g and 2g+1 share row-group g; one wave-pair merge + write
    if (t < 64) {
        int g = t >> 4, rr = t & 15;
        float va = red_v[2 * g][rr];     int ia = red_i[2 * g][rr];
        float vb = red_v[2 * g + 1][rr]; int ib = red_i[2 * g + 1][rr];
        bool tb = (vb > va) || (vb == va && ib < ia);
        int i = tb ? ib : ia;
        int p = p0 + t;
        tok_i[p] = i;
        tok_f[p] = (float)i;
    }
}

// ---------------- finalize: z_q gather + straight-through blend ----------------

__global__ void k_final(const float* __restrict__ z, const float* __restrict__ emb,
                        const int* __restrict__ tok, const float* __restrict__ inv_zn,
                        const float* __restrict__ en_inv, const float* __restrict__ en_norm,
                        float* __restrict__ zq, float* __restrict__ dec) {
    long gid = (long)blockIdx.x * 256 + threadIdx.x;   // 0..8388607
    int hw = (int)(gid & 1023);
    int b  = (int)(gid >> 19);
    int p  = (b << 10) | hw;
    int e  = (int)((gid >> 10) & 511);
    int tk = tok[p];
    float zqv = emb[(long)tk * Ee + e];
    float nq  = en_norm[tk];
    float nzq = zqv * en_inv[tk];
    float zv  = z[gid];
    float nz  = zv * inv_zn[p];
    zq[gid]  = zqv;
    dec[gid] = (nz + (nzq - nz)) * nq;
}

// ---------------- launch ----------------

extern "C" void kernel_launch(void* const* d_in, const int* in_sizes, int n_in,
                              void* d_out, int out_size, void* d_ws, size_t ws_size,
                              hipStream_t stream) {
    const float* x     = (const float*)d_in[0];
    const float* w_pre = (const float*)d_in[1];
    const float* b_pre = (const float*)d_in[2];
    const float* emb   = (const float*)d_in[3];

    float* out  = (float*)d_out;
    float* z    = out + O_Z;
    float* zq   = out + O_ZQ;
    float* dec  = out + O_DEC;
    float* tokf = out + O_TOK;
    float* embT = zq;            // z_q region reused as scratch until k_final

    float* ws      = (float*)d_ws;      // ~720 KB of d_ws used
    float* wT      = ws;                // 131072
    float* en_inv  = wT + 131072;       // 8192
    float* en_norm = en_inv + 8192;     // 8192
    float* inv_zn  = en_norm + 8192;    // 16384
    int*   tok_i   = (int*)(inv_zn + 16384); // 16384

    k_wT<<<512, 256, 0, stream>>>(w_pre, wT);
    k_en<<<2048, 256, 0, stream>>>(emb, en_inv, en_norm);
    k_embT<<<1024, 256, 0, stream>>>(emb, en_inv, embT);
    dim3 g1(Mm / 64, Ee / 64);
    k_gemm1<<<g1, 256, 0, stream>>>(x, wT, b_pre, z);
    k_znorm<<<Mm / 256, 256, 0, stream>>>(z, inv_zn);
    k_argmax<<<Mm / 64, 512, 0, stream>>>(z, inv_zn, embT, tok_i, tokf);
    k_final<<<(int)(8388608 / 256), 256, 0, stream>>>(z, emb, tok_i, inv_zn, en_inv, en_norm, zq, dec);
}

// Round 3
// 642.339 us; speedup vs baseline: 3.3092x; 2.7596x over previous
//
#include <hip/hip_runtime.h>
#include <math.h>

#define EPSF 1e-8f

constexpr int Bn = 16, Cc = 256, HW = 1024, Ee = 512, Vv = 8192;
constexpr int Mm = Bn * HW; // 16384 pixels

// d_out float offsets: z | z_q | decoder_input | tokens(float)
constexpr long O_Z   = 0;
constexpr long O_ZQ  = 8388608;
constexpr long O_DEC = 16777216;
constexpr long O_TOK = 25165824;

typedef __attribute__((ext_vector_type(8))) short bf16x8;
typedef __attribute__((ext_vector_type(4))) short bf16x4;
typedef __attribute__((ext_vector_type(4))) float f32x4;

__device__ __forceinline__ unsigned short f2bf(float x) {
    unsigned int u = __float_as_uint(x);
    unsigned int r = (u + 0x7FFFu + ((u >> 16) & 1u)) >> 16;   // RNE
    return (unsigned short)r;
}
__device__ __forceinline__ float bf2f(unsigned short h) {
    return __uint_as_float(((unsigned int)h) << 16);
}

// ---------------- small prep kernels ----------------

__global__ void k_wT(const float* __restrict__ w, float* __restrict__ wT) {
    int gid = blockIdx.x * 256 + threadIdx.x;      // 0..131071
    int c = gid >> 9, e = gid & 511;
    wT[gid] = w[e * Cc + c];                        // wT[c][e]
}

__global__ void k_en(const float* __restrict__ emb, float* __restrict__ en_inv,
                     float* __restrict__ en_norm) {
    int v = blockIdx.x * 4 + (threadIdx.x >> 6);    // one wave per row
    int lane = threadIdx.x & 63;
    const float* row = emb + (long)v * Ee;
    float s = 0.f;
#pragma unroll
    for (int j = 0; j < 8; ++j) { float xv = row[lane + 64 * j]; s += xv * xv; }
#pragma unroll
    for (int off = 32; off; off >>= 1) s += __shfl_xor(s, off);
    if (lane == 0) {
        float n = sqrtf(s);
        en_norm[v] = EPSF + n;
        en_inv[v]  = 1.0f / (EPSF + n);
    }
}

// ---------------- GEMM1: z[b][e][hw] = sum_c x[b][c][hw]*w[e][c] + b[e] ----------------

__global__ __launch_bounds__(256) void k_gemm1(const float* __restrict__ x,
                                               const float* __restrict__ wT,
                                               const float* __restrict__ bias,
                                               float* __restrict__ z) {
    __shared__ float As[32][64];
    __shared__ float Bs[32][64];
    int m0 = blockIdx.x * 64;                 // pixel tile
    int b = m0 >> 10, hw0 = m0 & 1023;
    int e0 = blockIdx.y * 64;
    int t = threadIdx.x;
    int mi = t >> 4, ni = t & 15;
    float acc[4][4] = {};
    for (int c0 = 0; c0 < Cc; c0 += 32) {
#pragma unroll
        for (int q = 0; q < 2; ++q) {
            int f = t + 256 * q;
            int kk = f >> 4, m4 = (f & 15) * 4;
            *(float4*)&As[kk][m4] = *(const float4*)(x + ((long)(b * Cc + c0 + kk)) * HW + hw0 + m4);
            *(float4*)&Bs[kk][m4] = *(const float4*)(wT + (long)(c0 + kk) * Ee + e0 + m4);
        }
        __syncthreads();
#pragma unroll
        for (int kk = 0; kk < 32; ++kk) {
            float4 a = *(float4*)&As[kk][mi * 4];
            float4 bv = *(float4*)&Bs[kk][ni * 4];
            float av[4] = {a.x, a.y, a.z, a.w};
            float bb[4] = {bv.x, bv.y, bv.z, bv.w};
#pragma unroll
            for (int r = 0; r < 4; ++r)
#pragma unroll
                for (int c = 0; c < 4; ++c) acc[r][c] = fmaf(av[r], bb[c], acc[r][c]);
        }
        __syncthreads();
    }
#pragma unroll
    for (int c = 0; c < 4; ++c) {
        int e = e0 + ni * 4 + c;
        float be = bias[e];
        float4 o = make_float4(acc[0][c] + be, acc[1][c] + be, acc[2][c] + be, acc[3][c] + be);
        *(float4*)(z + ((long)(b * Ee + e)) * HW + hw0 + mi * 4) = o;
    }
}

// per-pixel 1/(EPS+||z||) over E
__global__ void k_znorm(const float* __restrict__ z, float* __restrict__ inv_zn) {
    int p = blockIdx.x * 256 + threadIdx.x;
    int b = p >> 10, hw = p & 1023;
    const float* base = z + (long)b * Ee * HW + hw;
    float s = 0.f;
    for (int e = 0; e < Ee; ++e) { float xv = base[(long)e * HW]; s += xv * xv; }
    inv_zn[p] = 1.0f / (EPSF + sqrtf(s));
}

// ---------------- A split: zn -> A_hi/A_lo bf16 [16384][512] (pixel-major) ----------------

__global__ void k_Asplit(const float* __restrict__ z, const float* __restrict__ inv_zn,
                         unsigned short* __restrict__ Ahi, unsigned short* __restrict__ Alo) {
    __shared__ float tile[64][65];
    int p0 = (blockIdx.x >> 3) * 64;   // 256 p-tiles
    int e0 = (blockIdx.x & 7) * 64;    // 8 e-tiles
    int b = p0 >> 10, hw0 = p0 & 1023;
    int t = threadIdx.x;
#pragma unroll
    for (int q = 0; q < 4; ++q) {
        int f = t + 256 * q;
        int e_l = f >> 4, p4 = (f & 15) * 4;
        float4 d = *(const float4*)(z + ((long)(b * Ee + e0 + e_l)) * HW + hw0 + p4);
        tile[e_l][p4 + 0] = d.x; tile[e_l][p4 + 1] = d.y;
        tile[e_l][p4 + 2] = d.z; tile[e_l][p4 + 3] = d.w;
    }
    __syncthreads();
#pragma unroll
    for (int q = 0; q < 4; ++q) {
        int f = t + 256 * q;
        int p_l = f >> 4, e4 = (f & 15) * 4;
        float inv = inv_zn[p0 + p_l];
        bf16x4 h, lo;
#pragma unroll
        for (int j = 0; j < 4; ++j) {
            float xv = tile[e4 + j][p_l] * inv;
            unsigned short hh = f2bf(xv);
            h[j]  = (short)hh;
            lo[j] = (short)f2bf(xv - bf2f(hh));
        }
        long off = (long)(p0 + p_l) * Ee + e0 + e4;
        *(bf16x4*)(Ahi + off) = h;
        *(bf16x4*)(Alo + off) = lo;
    }
}

// ---------------- B split: emb*en_inv -> B_hi/B_lo bf16 [8192][512] (v-major) ----------------

__global__ void k_Bsplit(const float* __restrict__ emb, const float* __restrict__ en_inv,
                         unsigned short* __restrict__ Bhi, unsigned short* __restrict__ Blo) {
    int gid = blockIdx.x * 256 + threadIdx.x;   // 0..1048575
    int v = gid >> 7, c4 = (gid & 127) * 4;
    float inv = en_inv[v];
    float4 d = *(const float4*)(emb + (long)v * Ee + c4);
    float xs[4] = {d.x * inv, d.y * inv, d.z * inv, d.w * inv};
    bf16x4 h, lo;
#pragma unroll
    for (int j = 0; j < 4; ++j) {
        unsigned short hh = f2bf(xs[j]);
        h[j]  = (short)hh;
        lo[j] = (short)f2bf(xs[j] - bf2f(hh));
    }
    long off = (long)v * Ee + c4;
    *(bf16x4*)(Bhi + off) = h;
    *(bf16x4*)(Blo + off) = lo;
}

// ---------------- MFMA sims GEMM + per-block argmax ----------------
// 8192 blocks (128 m-tiles x 64 v-tiles), 256 thr = 4 waves (2x2).
// 3 segments: hiA*hiB + hiA*loB + loA*hiB accumulated in one f32 acc.
// LDS tiles [128 rows][64 k] bf16, 16B-slot XOR swizzle (slot ^= row&7).

__global__ __launch_bounds__(256, 2) void k_mfma(const unsigned short* __restrict__ Ahi,
                                                 const unsigned short* __restrict__ Alo,
                                                 const unsigned short* __restrict__ Bhi,
                                                 const unsigned short* __restrict__ Blo,
                                                 float* __restrict__ part_v,
                                                 int* __restrict__ part_i) {
    __shared__ short As[128 * 64];
    __shared__ short Bs[128 * 64];
    __shared__ float red_v[2][2][64];
    __shared__ int   red_i[2][2][64];

    int t = threadIdx.x;
    int wg = blockIdx.x;
    int xcd = wg & 7, r = wg >> 3;
    int bx = xcd * 16 + (r & 15);     // 0..127  (m-tile), XCD-chunked
    int by = r >> 4;                  // 0..63   (v-tile)
    long m0 = (long)bx * 128, n0 = (long)by * 128;

    int wid = t >> 6, l = t & 63;
    int wr = wid >> 1, wc = wid & 1;
    int srow = t >> 3, sslot = t & 7;
    int l15 = l & 15, lg = l >> 4;

    f32x4 zero4 = {0.f, 0.f, 0.f, 0.f};
    f32x4 acc[4][4];
#pragma unroll
    for (int i = 0; i < 4; ++i)
#pragma unroll
        for (int j = 0; j < 4; ++j) acc[i][j] = zero4;

    const unsigned short* Aseg[3] = {Ahi, Ahi, Alo};
    const unsigned short* Bseg[3] = {Bhi, Blo, Bhi};

    for (int seg = 0; seg < 3; ++seg) {
        const unsigned short* Ag = Aseg[seg];
        const unsigned short* Bg = Bseg[seg];
        for (int kt = 0; kt < 8; ++kt) {
            int k0 = kt * 64;
            bf16x8 ra[4], rb[4];
#pragma unroll
            for (int q = 0; q < 4; ++q) {
                int rr = srow + 32 * q;
                ra[q] = *(const bf16x8*)(Ag + (m0 + rr) * Ee + k0 + sslot * 8);
                rb[q] = *(const bf16x8*)(Bg + (n0 + rr) * Ee + k0 + sslot * 8);
            }
            __syncthreads();   // previous compute done reading LDS
#pragma unroll
            for (int q = 0; q < 4; ++q) {
                int rr = srow + 32 * q;
                int sw = (sslot ^ (rr & 7)) * 8;
                *(bf16x8*)&As[rr * 64 + sw] = ra[q];
                *(bf16x8*)&Bs[rr * 64 + sw] = rb[q];
            }
            __syncthreads();   // tiles visible
            bf16x8 af[4][2], bf[4][2];
#pragma unroll
            for (int mt = 0; mt < 4; ++mt)
#pragma unroll
                for (int kk = 0; kk < 2; ++kk) {
                    int row = wr * 64 + mt * 16 + l15;
                    int s = kk * 4 + lg;
                    af[mt][kk] = *(bf16x8*)&As[row * 64 + ((s ^ (row & 7)) * 8)];
                    int nrow = wc * 64 + mt * 16 + l15;
                    bf[mt][kk] = *(bf16x8*)&Bs[nrow * 64 + ((s ^ (nrow & 7)) * 8)];
                }
#pragma unroll
            for (int kk = 0; kk < 2; ++kk)
#pragma unroll
                for (int mt = 0; mt < 4; ++mt)
#pragma unroll
                    for (int nt = 0; nt < 4; ++nt)
                        acc[mt][nt] = __builtin_amdgcn_mfma_f32_16x16x32_bf16(
                            af[mt][kk], bf[nt][kk], acc[mt][nt], 0, 0, 0);
        }
    }

    // ---- per-block argmax epilogue ----
    // C/D layout: col = l&15, row = (l>>4)*4 + rg  [verified mapping]
#pragma unroll
    for (int mt = 0; mt < 4; ++mt)
#pragma unroll
        for (int rg = 0; rg < 4; ++rg) {
            float best = -1e30f; int bi = 0x7FFFFFFF;
#pragma unroll
            for (int nt = 0; nt < 4; ++nt) {
                float val = acc[mt][nt][rg];
                int idx = (int)n0 + wc * 64 + nt * 16 + l15;
                if (val > best) { best = val; bi = idx; }
            }
#pragma unroll
            for (int off = 1; off < 16; off <<= 1) {
                float ov = __shfl_xor(best, off);
                int oi = __shfl_xor(bi, off);
                if (ov > best || (ov == best && oi < bi)) { best = ov; bi = oi; }
            }
            if (l15 == 0) {
                int rloc = mt * 16 + lg * 4 + rg;
                red_v[wr][wc][rloc] = best;
                red_i[wr][wc][rloc] = bi;
            }
        }
    __syncthreads();
    if (t < 128) {
        int wr_ = t >> 6, rloc = t & 63;
        float va = red_v[wr_][0][rloc]; int ia = red_i[wr_][0][rloc];
        float vb = red_v[wr_][1][rloc]; int ib = red_i[wr_][1][rloc];
        if (vb > va || (vb == va && ib < ia)) { va = vb; ia = ib; }
        long m = m0 + wr_ * 64 + rloc;
        part_v[m * 64 + by] = va;
        part_i[m * 64 + by] = ia;
    }
}

// ---------------- merge 64 partials per pixel ----------------

__global__ void k_reduce(const float* __restrict__ part_v, const int* __restrict__ part_i,
                         int* __restrict__ tok_i, float* __restrict__ tok_f) {
    int p = blockIdx.x * 4 + (threadIdx.x >> 6);
    int lane = threadIdx.x & 63;
    float v = part_v[(long)p * 64 + lane];
    int i = part_i[(long)p * 64 + lane];
#pragma unroll
    for (int off = 1; off < 64; off <<= 1) {
        float ov = __shfl_xor(v, off);
        int oi = __shfl_xor(i, off);
        if (ov > v || (ov == v && oi < i)) { v = ov; i = oi; }
    }
    if (lane == 0) { tok_i[p] = i; tok_f[p] = (float)i; }
}

// ---------------- finalize: z_q gather + straight-through blend ----------------

__global__ void k_final(const float* __restrict__ z, const float* __restrict__ emb,
                        const int* __restrict__ tok, const float* __restrict__ inv_zn,
                        const float* __restrict__ en_inv, const float* __restrict__ en_norm,
                        float* __restrict__ zq, float* __restrict__ dec) {
    long gid = (long)blockIdx.x * 256 + threadIdx.x;   // 0..8388607
    int hw = (int)(gid & 1023);
    int b  = (int)(gid >> 19);
    int p  = (b << 10) | hw;
    int e  = (int)((gid >> 10) & 511);
    int tk = tok[p];
    float zqv = emb[(long)tk * Ee + e];
    float nq  = en_norm[tk];
    float nzq = zqv * en_inv[tk];
    float zv  = z[gid];
    float nz  = zv * inv_zn[p];
    zq[gid]  = zqv;
    dec[gid] = (nz + (nzq - nz)) * nq;
}

// ---------------- launch ----------------

extern "C" void kernel_launch(void* const* d_in, const int* in_sizes, int n_in,
                              void* d_out, int out_size, void* d_ws, size_t ws_size,
                              hipStream_t stream) {
    const float* x     = (const float*)d_in[0];
    const float* w_pre = (const float*)d_in[1];
    const float* b_pre = (const float*)d_in[2];
    const float* emb   = (const float*)d_in[3];

    float* out  = (float*)d_out;
    float* z    = out + O_Z;
    float* zq   = out + O_ZQ;
    float* dec  = out + O_DEC;
    float* tokf = out + O_TOK;

    // zq region (32MB): A_hi | A_lo   (dead until k_final)
    unsigned short* Ahi = (unsigned short*)zq;
    unsigned short* Alo = Ahi + (long)Mm * Ee;
    // dec region (32MB): B_hi | B_lo | part_v | part_i
    unsigned short* Bhi = (unsigned short*)dec;
    unsigned short* Blo = Bhi + (long)Vv * Ee;
    float* part_v = dec + 4 * 1024 * 1024;           // +16MB
    int*   part_i = (int*)(dec + 5 * 1024 * 1024);   // +20MB

    float* ws      = (float*)d_ws;
    float* wT      = ws;                // 131072
    float* en_inv  = wT + 131072;       // 8192
    float* en_norm = en_inv + 8192;     // 8192
    float* inv_zn  = en_norm + 8192;    // 16384
    int*   tok_i   = (int*)(inv_zn + 16384); // 16384

    k_wT<<<512, 256, 0, stream>>>(w_pre, wT);
    k_en<<<2048, 256, 0, stream>>>(emb, en_inv, en_norm);
    dim3 g1(Mm / 64, Ee / 64);
    k_gemm1<<<g1, 256, 0, stream>>>(x, wT, b_pre, z);
    k_znorm<<<Mm / 256, 256, 0, stream>>>(z, inv_zn);
    k_Asplit<<<2048, 256, 0, stream>>>(z, inv_zn, Ahi, Alo);
    k_Bsplit<<<4096, 256, 0, stream>>>(emb, en_inv, Bhi, Blo);
    k_mfma<<<8192, 256, 0, stream>>>(Ahi, Alo, Bhi, Blo, part_v, part_i);
    k_reduce<<<Mm / 4, 256, 0, stream>>>(part_v, part_i, tok_i, tokf);
    k_final<<<(int)(8388608 / 256), 256, 0, stream>>>(z, emb, tok_i, inv_zn, en_inv, en_norm, zq, dec);
}